// Round 16
// baseline (241.527 us; speedup 1.0000x reference)
//
#include <hip/hip_runtime.h>
#include <math.h>

// 10-layer MLP, ALL-K16 MFMA (16x16x16f16), activations REGISTER-RESIDENT.
// Structure (validated R11-R14): D-layout of 16x16x16f16 == its B-frag
// layout, so layers chain acc->B-frag entirely in registers; LDS holds 47
// x16 weight frags (24 KB, linear b64 reads, 0 bank conflicts); bias via
// augmented-K column + 1.0 marker (R13 scheme; R15's bias-C cost 48 regs).
// R16: T=1 tile/wave + 512-thread blocks + launch_bounds(512,6).
// Empirical gfx950 rule (R6/R13/R14): unified reg budget ~= 512/min_waves;
// T=1 live set ~50 << 85 (w=6) -> zero spills AND 24 waves/CU (75% ceiling
// vs R13's 16). Block=512 shares one 24KB weight copy across 8 waves
// (3 blocks/CU = 72KB LDS). Per-wave ILP drops; 6 waves/SIMD TLP replaces it.

typedef _Float16 half4 __attribute__((ext_vector_type(4)));
typedef _Float16 half2 __attribute__((ext_vector_type(2)));
typedef float f32x4 __attribute__((ext_vector_type(4)));

#define T 1  // 16-row tiles in flight per wave

__device__ __forceinline__ float swish_f(float a) {
    float e = __expf(-a);
    return a * __builtin_amdgcn_rcpf(1.0f + e);
}

__device__ __forceinline__ half4 pack4(const float (&v)[4]) {
    auto lo = __builtin_amdgcn_cvt_pkrtz(v[0], v[1]);
    auto hi = __builtin_amdgcn_cvt_pkrtz(v[2], v[3]);
    union {
        half4 h4;
        half2 h2[2];
    } u;
    u.h2[0] = __builtin_bit_cast(half2, lo);
    u.h2[1] = __builtin_bit_cast(half2, hi);
    return u.h4;
}

// x16 weight frag (K=16, k=kb+kg*4+e): row=ot*16+lr; k==IN -> bias.
__device__ __forceinline__ half4 make_frag16(const float* __restrict__ W,
                                             const float* __restrict__ b,
                                             int IN, int OUT, int ot, int kb,
                                             int lr, int kg) {
    const int r = ot * 16 + lr;
    half4 h;
#pragma unroll
    for (int e = 0; e < 4; ++e) {
        const int k = kb + kg * 4 + e;
        float v = 0.0f;
        if (r < OUT) {
            if (k < IN)
                v = W[r * IN + k];
            else if (k == IN)
                v = b[r];
        }
        h[e] = (_Float16)v;
    }
    return h;
}

// One layer for all T tiles, register-chained.
// bf[t][0..NKT-1] in (x16 B-frag layout) -> bf[t][0..NOT-1] out.
// MARK = OUT = next layer's bias column.
template <int NKT, int NOT, int MARK>
__device__ __forceinline__ void layerR(const _Float16* __restrict__ wb,
                                       half4 (&bf)[T][3], int lane, int kg) {
    const f32x4 z4 = {0.f, 0.f, 0.f, 0.f};
    f32x4 acc[T][NOT];
#pragma unroll
    for (int kt = 0; kt < NKT; ++kt) {
#pragma unroll
        for (int ot = 0; ot < NOT; ++ot) {
            const half4 wg =
                *(const half4*)(wb + (ot * NKT + kt) * 256 + lane * 4);
#pragma unroll
            for (int t = 0; t < T; ++t)
                acc[t][ot] = __builtin_amdgcn_mfma_f32_16x16x16f16(
                    wg, bf[t][kt], kt == 0 ? z4 : acc[t][ot], 0, 0, 0);
        }
    }
#pragma unroll
    for (int t = 0; t < T; ++t) {
#pragma unroll
        for (int ot = 0; ot < NOT; ++ot) {
            float v[4];
#pragma unroll
            for (int r = 0; r < 4; ++r) {
                v[r] = swish_f(acc[t][ot][r]);
                if (ot == MARK / 16 && ot * 16 + kg * 4 + r == MARK)
                    v[r] = 1.0f;
            }
            bf[t][ot] = pack4(v);
        }
    }
}

__device__ __forceinline__ half4 load_x4(const float* __restrict__ x,
                                         int row0, int lr, int kg) {
    half4 b = {};
    const float* xr = x + (size_t)(row0 + lr) * 11;
#pragma unroll
    for (int e = 0; e < 4; ++e) {
        const int k = kg * 4 + e;
        float v = (k < 11) ? xr[k] : ((k == 11) ? 1.0f : 0.0f);
        b[e] = (_Float16)v;
    }
    return b;
}

__global__ __launch_bounds__(512, 6) void longnet_mlp_r16(
    const float* __restrict__ x,
    const float* __restrict__ W0, const float* __restrict__ b0,
    const float* __restrict__ W1, const float* __restrict__ b1,
    const float* __restrict__ W2, const float* __restrict__ b2,
    const float* __restrict__ W3, const float* __restrict__ b3,
    const float* __restrict__ W4, const float* __restrict__ b4,
    const float* __restrict__ W5, const float* __restrict__ b5,
    const float* __restrict__ W6, const float* __restrict__ b6,
    const float* __restrict__ W7, const float* __restrict__ b7,
    const float* __restrict__ W8, const float* __restrict__ b8,
    const float* __restrict__ W9, const float* __restrict__ b9,
    float* __restrict__ out, int n) {
    // LDS: 47 x16 weight frags x 512 B = 24064 B, shared by 8 waves.
    __shared__ __align__(16) _Float16 s_w[47 * 256];

    const int tid = threadIdx.x;
    const int lane = tid & 63;
    const int wave = tid >> 6;  // 0..7
    const int lr = lane & 15;
    const int kg = lane >> 4;

    // ---- stage 47 weight frags (8 waves round-robin) ----
    {
        const float* Wt[10] = {W0, W1, W2, W3, W4, W5, W6, W7, W8, W9};
        const float* bt[10] = {b0, b1, b2, b3, b4, b5, b6, b7, b8, b9};
        const int INs[10] = {11, 20, 20, 30, 30, 40, 40, 40, 20, 10};
        const int OUTs[10] = {20, 20, 30, 30, 40, 40, 40, 20, 10, 1};
        const int NOTs[10] = {2, 2, 2, 2, 3, 3, 3, 2, 1, 1};
        const int NKTs[10] = {1, 2, 2, 2, 2, 3, 3, 3, 2, 1};
        int f = 0;
        for (int L = 0; L < 10; ++L)
            for (int ot = 0; ot < NOTs[L]; ++ot)
                for (int kt = 0; kt < NKTs[L]; ++kt, ++f)
                    if ((f & 7) == wave) {
                        half4 h = make_frag16(Wt[L], bt[L], INs[L], OUTs[L],
                                              ot, kt * 16, lr, kg);
                        *(half4*)(s_w + f * 256 + lane * 4) = h;
                    }
    }
    __syncthreads();

    const f32x4 z4 = {0.f, 0.f, 0.f, 0.f};
    const int ngrp = n >> 4;  // 16-row groups; n = 2e6 -> 125000 exact
    const int step = (int)gridDim.x * 8;

    for (int g = blockIdx.x * 8 + wave; g < ngrp; g += step) {
        const int row0 = g * 16;

        half4 bf[T][3];
        bf[0][0] = load_x4(x, row0, lr, kg);

        layerR<1, 2, 20>(s_w + 0 * 256, bf, lane, kg);   // L0 11->20
        layerR<2, 2, 20>(s_w + 2 * 256, bf, lane, kg);   // L1 20->20
        layerR<2, 2, 30>(s_w + 6 * 256, bf, lane, kg);   // L2 20->30
        layerR<2, 2, 30>(s_w + 10 * 256, bf, lane, kg);  // L3 30->30
        layerR<2, 3, 40>(s_w + 14 * 256, bf, lane, kg);  // L4 30->40
        layerR<3, 3, 40>(s_w + 20 * 256, bf, lane, kg);  // L5 40->40
        layerR<3, 3, 40>(s_w + 29 * 256, bf, lane, kg);  // L6 40->40
        layerR<3, 2, 20>(s_w + 38 * 256, bf, lane, kg);  // L7 40->20
        layerR<2, 1, 10>(s_w + 44 * 256, bf, lane, kg);  // L8 20->10

        // L9 (10->1) + ReLU: feature 0 at kg==0, reg 0; sample = lr.
        {
            const half4 wg = *(const half4*)(s_w + 46 * 256 + lane * 4);
            f32x4 F = __builtin_amdgcn_mfma_f32_16x16x16f16(wg, bf[0][0], z4,
                                                            0, 0, 0);
            if (kg == 0) out[row0 + lr] = fmaxf(F[0], 0.0f);
        }
    }
}

extern "C" void kernel_launch(void* const* d_in, const int* in_sizes, int n_in,
                              void* d_out, int out_size, void* d_ws, size_t ws_size,
                              hipStream_t stream) {
    const float* x = (const float*)d_in[0];
    const float* W0 = (const float*)d_in[1];
    const float* b0 = (const float*)d_in[2];
    const float* W1 = (const float*)d_in[3];
    const float* b1 = (const float*)d_in[4];
    const float* W2 = (const float*)d_in[5];
    const float* b2 = (const float*)d_in[6];
    const float* W3 = (const float*)d_in[7];
    const float* b3 = (const float*)d_in[8];
    const float* W4 = (const float*)d_in[9];
    const float* b4 = (const float*)d_in[10];
    const float* W5 = (const float*)d_in[11];
    const float* b5 = (const float*)d_in[12];
    const float* W6 = (const float*)d_in[13];
    const float* b6 = (const float*)d_in[14];
    const float* W7 = (const float*)d_in[15];
    const float* b7 = (const float*)d_in[16];
    const float* W8 = (const float*)d_in[17];
    const float* b8 = (const float*)d_in[18];
    const float* W9 = (const float*)d_in[19];
    const float* b9 = (const float*)d_in[20];
    float* out = (float*)d_out;

    const int n = in_sizes[0] / 11;  // 2,000,000 rows (divisible by 16)
    const int grid = 768;            // 3 blocks/CU resident (72KB LDS/CU)

    longnet_mlp_r16<<<grid, 512, 0, stream>>>(
        x, W0, b0, W1, b1, W2, b2, W3, b3, W4, b4, W5, b5, W6, b6, W7, b7, W8,
        b8, W9, b9, out, n);
}

// Round 17
// 179.038 us; speedup vs baseline: 1.3490x; 1.3490x over previous
//
#include <hip/hip_runtime.h>
#include <math.h>

// 10-layer MLP, ALL-K16 MFMA (16x16x16f16), activations REGISTER-RESIDENT.
// Structure (validated R11-R16): D-layout of 16x16x16f16 == its B-frag
// layout, so layers chain acc->B-frag entirely in registers; LDS holds 47
// x16 weight frags (24 KB, linear b64 reads, 0 bank conflicts); bias via
// augmented-K column + 1.0 marker.
// R17: T=1 tile/wave, block=256, launch_bounds(256,2), grid 1536.
// Allocator rule (R4/R6/R10/R13/R14/R16): forced min-waves >=4 shrinks the
// unified reg budget below the live set -> scratch spills (R16: 40 VGPR,
// 82MB writes). (256,2) allocates naturally with zero scratch. T=1 live set
// ~60 unified -> <=85 -> 6 waves/SIMD permitted; LDS 24KB x 6 blocks/CU =
// 144KB fits -> 24 waves/CU ceiling (75%) vs R13's ~11. TLP replaces ILP.

typedef _Float16 half4 __attribute__((ext_vector_type(4)));
typedef _Float16 half2 __attribute__((ext_vector_type(2)));
typedef float f32x4 __attribute__((ext_vector_type(4)));

__device__ __forceinline__ float swish_f(float a) {
    float e = __expf(-a);
    return a * __builtin_amdgcn_rcpf(1.0f + e);
}

__device__ __forceinline__ half4 pack4(const float (&v)[4]) {
    auto lo = __builtin_amdgcn_cvt_pkrtz(v[0], v[1]);
    auto hi = __builtin_amdgcn_cvt_pkrtz(v[2], v[3]);
    union {
        half4 h4;
        half2 h2[2];
    } u;
    u.h2[0] = __builtin_bit_cast(half2, lo);
    u.h2[1] = __builtin_bit_cast(half2, hi);
    return u.h4;
}

// x16 weight frag (K=16, k=kb+kg*4+e): row=ot*16+lr; k==IN -> bias.
__device__ __forceinline__ half4 make_frag16(const float* __restrict__ W,
                                             const float* __restrict__ b,
                                             int IN, int OUT, int ot, int kb,
                                             int lr, int kg) {
    const int r = ot * 16 + lr;
    half4 h;
#pragma unroll
    for (int e = 0; e < 4; ++e) {
        const int k = kb + kg * 4 + e;
        float v = 0.0f;
        if (r < OUT) {
            if (k < IN)
                v = W[r * IN + k];
            else if (k == IN)
                v = b[r];
        }
        h[e] = (_Float16)v;
    }
    return h;
}

// One layer, register-chained. bf[0..NKT-1] in (x16 B-frag layout) ->
// bf[0..NOT-1] out. MARK = OUT = next layer's bias column.
template <int NKT, int NOT, int MARK>
__device__ __forceinline__ void layerR(const _Float16* __restrict__ wb,
                                       half4 (&bf)[3], int lane, int kg) {
    const f32x4 z4 = {0.f, 0.f, 0.f, 0.f};
    f32x4 acc[NOT];
#pragma unroll
    for (int kt = 0; kt < NKT; ++kt) {
#pragma unroll
        for (int ot = 0; ot < NOT; ++ot) {
            const half4 wg =
                *(const half4*)(wb + (ot * NKT + kt) * 256 + lane * 4);
            acc[ot] = __builtin_amdgcn_mfma_f32_16x16x16f16(
                wg, bf[kt], kt == 0 ? z4 : acc[ot], 0, 0, 0);
        }
    }
#pragma unroll
    for (int ot = 0; ot < NOT; ++ot) {
        float v[4];
#pragma unroll
        for (int r = 0; r < 4; ++r) {
            v[r] = swish_f(acc[ot][r]);
            if (ot == MARK / 16 && ot * 16 + kg * 4 + r == MARK) v[r] = 1.0f;
        }
        bf[ot] = pack4(v);
    }
}

__device__ __forceinline__ half4 load_x4(const float* __restrict__ x,
                                         int row0, int lr, int kg) {
    half4 b = {};
    const float* xr = x + (size_t)(row0 + lr) * 11;
#pragma unroll
    for (int e = 0; e < 4; ++e) {
        const int k = kg * 4 + e;
        float v = (k < 11) ? xr[k] : ((k == 11) ? 1.0f : 0.0f);
        b[e] = (_Float16)v;
    }
    return b;
}

__global__ __launch_bounds__(256, 2) void longnet_mlp_r17(
    const float* __restrict__ x,
    const float* __restrict__ W0, const float* __restrict__ b0,
    const float* __restrict__ W1, const float* __restrict__ b1,
    const float* __restrict__ W2, const float* __restrict__ b2,
    const float* __restrict__ W3, const float* __restrict__ b3,
    const float* __restrict__ W4, const float* __restrict__ b4,
    const float* __restrict__ W5, const float* __restrict__ b5,
    const float* __restrict__ W6, const float* __restrict__ b6,
    const float* __restrict__ W7, const float* __restrict__ b7,
    const float* __restrict__ W8, const float* __restrict__ b8,
    const float* __restrict__ W9, const float* __restrict__ b9,
    float* __restrict__ out, int n) {
    // LDS: 47 x16 weight frags x 512 B = 24064 B, shared by 4 waves.
    __shared__ __align__(16) _Float16 s_w[47 * 256];

    const int tid = threadIdx.x;
    const int lane = tid & 63;
    const int wave = tid >> 6;
    const int lr = lane & 15;
    const int kg = lane >> 4;

    // ---- stage 47 weight frags (4 waves round-robin) ----
    {
        const float* Wt[10] = {W0, W1, W2, W3, W4, W5, W6, W7, W8, W9};
        const float* bt[10] = {b0, b1, b2, b3, b4, b5, b6, b7, b8, b9};
        const int INs[10] = {11, 20, 20, 30, 30, 40, 40, 40, 20, 10};
        const int OUTs[10] = {20, 20, 30, 30, 40, 40, 40, 20, 10, 1};
        const int NOTs[10] = {2, 2, 2, 2, 3, 3, 3, 2, 1, 1};
        const int NKTs[10] = {1, 2, 2, 2, 2, 3, 3, 3, 2, 1};
        int f = 0;
        for (int L = 0; L < 10; ++L)
            for (int ot = 0; ot < NOTs[L]; ++ot)
                for (int kt = 0; kt < NKTs[L]; ++kt, ++f)
                    if ((f & 3) == wave) {
                        half4 h = make_frag16(Wt[L], bt[L], INs[L], OUTs[L],
                                              ot, kt * 16, lr, kg);
                        *(half4*)(s_w + f * 256 + lane * 4) = h;
                    }
    }
    __syncthreads();

    const f32x4 z4 = {0.f, 0.f, 0.f, 0.f};
    const int ngrp = n >> 4;  // 16-row groups; n = 2e6 -> 125000 exact
    const int step = (int)gridDim.x * 4;

    for (int g = blockIdx.x * 4 + wave; g < ngrp; g += step) {
        const int row0 = g * 16;

        half4 bf[3];
        bf[0] = load_x4(x, row0, lr, kg);

        layerR<1, 2, 20>(s_w + 0 * 256, bf, lane, kg);   // L0 11->20
        layerR<2, 2, 20>(s_w + 2 * 256, bf, lane, kg);   // L1 20->20
        layerR<2, 2, 30>(s_w + 6 * 256, bf, lane, kg);   // L2 20->30
        layerR<2, 2, 30>(s_w + 10 * 256, bf, lane, kg);  // L3 30->30
        layerR<2, 3, 40>(s_w + 14 * 256, bf, lane, kg);  // L4 30->40
        layerR<3, 3, 40>(s_w + 20 * 256, bf, lane, kg);  // L5 40->40
        layerR<3, 3, 40>(s_w + 29 * 256, bf, lane, kg);  // L6 40->40
        layerR<3, 2, 20>(s_w + 38 * 256, bf, lane, kg);  // L7 40->20
        layerR<2, 1, 10>(s_w + 44 * 256, bf, lane, kg);  // L8 20->10

        // L9 (10->1) + ReLU: feature 0 at kg==0, reg 0; sample = lr.
        {
            const half4 wg = *(const half4*)(s_w + 46 * 256 + lane * 4);
            f32x4 F = __builtin_amdgcn_mfma_f32_16x16x16f16(wg, bf[0], z4, 0,
                                                            0, 0);
            if (kg == 0) out[row0 + lr] = fmaxf(F[0], 0.0f);
        }
    }
}

extern "C" void kernel_launch(void* const* d_in, const int* in_sizes, int n_in,
                              void* d_out, int out_size, void* d_ws, size_t ws_size,
                              hipStream_t stream) {
    const float* x = (const float*)d_in[0];
    const float* W0 = (const float*)d_in[1];
    const float* b0 = (const float*)d_in[2];
    const float* W1 = (const float*)d_in[3];
    const float* b1 = (const float*)d_in[4];
    const float* W2 = (const float*)d_in[5];
    const float* b2 = (const float*)d_in[6];
    const float* W3 = (const float*)d_in[7];
    const float* b3 = (const float*)d_in[8];
    const float* W4 = (const float*)d_in[9];
    const float* b4 = (const float*)d_in[10];
    const float* W5 = (const float*)d_in[11];
    const float* b5 = (const float*)d_in[12];
    const float* W6 = (const float*)d_in[13];
    const float* b6 = (const float*)d_in[14];
    const float* W7 = (const float*)d_in[15];
    const float* b7 = (const float*)d_in[16];
    const float* W8 = (const float*)d_in[17];
    const float* b8 = (const float*)d_in[18];
    const float* W9 = (const float*)d_in[19];
    const float* b9 = (const float*)d_in[20];
    float* out = (float*)d_out;

    const int n = in_sizes[0] / 11;  // 2,000,000 rows (divisible by 16)
    const int grid = 1536;           // 6 blocks/CU persistent (144KB LDS/CU)

    longnet_mlp_r17<<<grid, 256, 0, stream>>>(
        x, W0, b0, W1, b1, W2, b2, W3, b3, W4, b4, W5, b5, W6, b6, W7, b7, W8,
        b8, W9, b9, out, n);
}

// Round 18
// 178.007 us; speedup vs baseline: 1.3568x; 1.0058x over previous
//
#include <hip/hip_runtime.h>
#include <math.h>

// 10-layer MLP, ALL-K16 MFMA (16x16x16f16), activations REGISTER-RESIDENT.
// Structure (validated R11-R17): D-layout of 16x16x16f16 == its B-frag
// layout, so layers chain acc->B-frag entirely in registers; LDS holds 47
// x16 weight frags (24 KB, linear b64 reads, 0 bank conflicts); bias via
// augmented-K column + 1.0 marker.
// R18: swish computed on float2 vectors -> v_pk_mul_f32/v_pk_add_f32 packed
// fp32 (CDNA4) halve the full-rate VALU in the epilogue (the non-trans ~40%
// of swish cost). T=2 tiles/wave (best ILP, R13), launch_bounds(256,2)
// (zero-spill, R14-verified), grid 1024. Occupancy is pinned at 3-4
// waves/SIMD by unified reg demand (R13/R14/R17 all ~36%); this round cuts
// VALU work instead of chasing residency.

typedef _Float16 half4 __attribute__((ext_vector_type(4)));
typedef _Float16 half2 __attribute__((ext_vector_type(2)));
typedef float f32x4 __attribute__((ext_vector_type(4)));
typedef float f32x2 __attribute__((ext_vector_type(2)));

#define T 2  // 16-row tiles in flight per wave

// swish on 2 lanes-elements at once: packed muls/adds + 2 trans each.
__device__ __forceinline__ f32x2 swish2(f32x2 a) {
    const f32x2 nl2e = {-1.442695041f, -1.442695041f};
    f32x2 t = a * nl2e;  // v_pk_mul_f32
    f32x2 e = {__builtin_amdgcn_exp2f(t.x), __builtin_amdgcn_exp2f(t.y)};
    const f32x2 one = {1.0f, 1.0f};
    f32x2 d = e + one;  // v_pk_add_f32
    f32x2 r = {__builtin_amdgcn_rcpf(d.x), __builtin_amdgcn_rcpf(d.y)};
    return a * r;  // v_pk_mul_f32
}

__device__ __forceinline__ half4 pack4v(f32x2 lo, f32x2 hi) {
    auto l = __builtin_amdgcn_cvt_pkrtz(lo.x, lo.y);
    auto h = __builtin_amdgcn_cvt_pkrtz(hi.x, hi.y);
    union {
        half4 h4;
        half2 h2[2];
    } u;
    u.h2[0] = __builtin_bit_cast(half2, l);
    u.h2[1] = __builtin_bit_cast(half2, h);
    return u.h4;
}

// x16 weight frag (K=16, k=kb+kg*4+e): row=ot*16+lr; k==IN -> bias.
__device__ __forceinline__ half4 make_frag16(const float* __restrict__ W,
                                             const float* __restrict__ b,
                                             int IN, int OUT, int ot, int kb,
                                             int lr, int kg) {
    const int r = ot * 16 + lr;
    half4 h;
#pragma unroll
    for (int e = 0; e < 4; ++e) {
        const int k = kb + kg * 4 + e;
        float v = 0.0f;
        if (r < OUT) {
            if (k < IN)
                v = W[r * IN + k];
            else if (k == IN)
                v = b[r];
        }
        h[e] = (_Float16)v;
    }
    return h;
}

// One layer for all T tiles, register-chained.
// bf[t][0..NKT-1] in (x16 B-frag layout) -> bf[t][0..NOT-1] out.
// MARK = OUT = next layer's bias column. The marker condition prunes to a
// single cndmask on one component of one ot (only one r satisfies mod-4).
template <int NKT, int NOT, int MARK>
__device__ __forceinline__ void layerR(const _Float16* __restrict__ wb,
                                       half4 (&bf)[T][3], int lane, int kg) {
    const f32x4 z4 = {0.f, 0.f, 0.f, 0.f};
    f32x4 acc[T][NOT];
#pragma unroll
    for (int kt = 0; kt < NKT; ++kt) {
#pragma unroll
        for (int ot = 0; ot < NOT; ++ot) {
            const half4 wg =
                *(const half4*)(wb + (ot * NKT + kt) * 256 + lane * 4);
#pragma unroll
            for (int t = 0; t < T; ++t)
                acc[t][ot] = __builtin_amdgcn_mfma_f32_16x16x16f16(
                    wg, bf[t][kt], kt == 0 ? z4 : acc[t][ot], 0, 0, 0);
        }
    }
#pragma unroll
    for (int t = 0; t < T; ++t) {
#pragma unroll
        for (int ot = 0; ot < NOT; ++ot) {
            f32x2 lo = {acc[t][ot][0], acc[t][ot][1]};
            f32x2 hi = {acc[t][ot][2], acc[t][ot][3]};
            lo = swish2(lo);
            hi = swish2(hi);
            if (ot == MARK / 16) {
#pragma unroll
                for (int r = 0; r < 4; ++r) {
                    if ((MARK & 15) % 4 == r) {  // compile-time r select
                        const bool m = (ot * 16 + kg * 4 + r == MARK);
                        if (r < 2) {
                            if (r == 0) lo.x = m ? 1.0f : lo.x;
                            if (r == 1) lo.y = m ? 1.0f : lo.y;
                        } else {
                            if (r == 2) hi.x = m ? 1.0f : hi.x;
                            if (r == 3) hi.y = m ? 1.0f : hi.y;
                        }
                    }
                }
            }
            bf[t][ot] = pack4v(lo, hi);
        }
    }
}

__device__ __forceinline__ half4 load_x4(const float* __restrict__ x,
                                         int row0, int lr, int kg) {
    half4 b = {};
    const float* xr = x + (size_t)(row0 + lr) * 11;
#pragma unroll
    for (int e = 0; e < 4; ++e) {
        const int k = kg * 4 + e;
        float v = (k < 11) ? xr[k] : ((k == 11) ? 1.0f : 0.0f);
        b[e] = (_Float16)v;
    }
    return b;
}

__global__ __launch_bounds__(256, 2) void longnet_mlp_r18(
    const float* __restrict__ x,
    const float* __restrict__ W0, const float* __restrict__ b0,
    const float* __restrict__ W1, const float* __restrict__ b1,
    const float* __restrict__ W2, const float* __restrict__ b2,
    const float* __restrict__ W3, const float* __restrict__ b3,
    const float* __restrict__ W4, const float* __restrict__ b4,
    const float* __restrict__ W5, const float* __restrict__ b5,
    const float* __restrict__ W6, const float* __restrict__ b6,
    const float* __restrict__ W7, const float* __restrict__ b7,
    const float* __restrict__ W8, const float* __restrict__ b8,
    const float* __restrict__ W9, const float* __restrict__ b9,
    float* __restrict__ out, int n) {
    // LDS: 47 x16 weight frags x 512 B = 24064 B. No activation LDS.
    __shared__ __align__(16) _Float16 s_w[47 * 256];

    const int tid = threadIdx.x;
    const int lane = tid & 63;
    const int wave = tid >> 6;
    const int lr = lane & 15;
    const int kg = lane >> 4;

    // ---- stage 47 weight frags (4 waves round-robin) ----
    {
        const float* Wt[10] = {W0, W1, W2, W3, W4, W5, W6, W7, W8, W9};
        const float* bt[10] = {b0, b1, b2, b3, b4, b5, b6, b7, b8, b9};
        const int INs[10] = {11, 20, 20, 30, 30, 40, 40, 40, 20, 10};
        const int OUTs[10] = {20, 20, 30, 30, 40, 40, 40, 20, 10, 1};
        const int NOTs[10] = {2, 2, 2, 2, 3, 3, 3, 2, 1, 1};
        const int NKTs[10] = {1, 2, 2, 2, 2, 3, 3, 3, 2, 1};
        int f = 0;
        for (int L = 0; L < 10; ++L)
            for (int ot = 0; ot < NOTs[L]; ++ot)
                for (int kt = 0; kt < NKTs[L]; ++kt, ++f)
                    if ((f & 3) == wave) {
                        half4 h = make_frag16(Wt[L], bt[L], INs[L], OUTs[L],
                                              ot, kt * 16, lr, kg);
                        *(half4*)(s_w + f * 256 + lane * 4) = h;
                    }
    }
    __syncthreads();

    const f32x4 z4 = {0.f, 0.f, 0.f, 0.f};
    const int ngrp = n >> 5;  // 32-row groups; n = 2e6 -> 62500 exact
    const int step = (int)gridDim.x * 4;

    for (int g = blockIdx.x * 4 + wave; g < ngrp; g += step) {
        const int row0 = g * 32;

        half4 bf[T][3];
#pragma unroll
        for (int t = 0; t < T; ++t)
            bf[t][0] = load_x4(x, row0 + t * 16, lr, kg);

        layerR<1, 2, 20>(s_w + 0 * 256, bf, lane, kg);   // L0 11->20
        layerR<2, 2, 20>(s_w + 2 * 256, bf, lane, kg);   // L1 20->20
        layerR<2, 2, 30>(s_w + 6 * 256, bf, lane, kg);   // L2 20->30
        layerR<2, 2, 30>(s_w + 10 * 256, bf, lane, kg);  // L3 30->30
        layerR<2, 3, 40>(s_w + 14 * 256, bf, lane, kg);  // L4 30->40
        layerR<3, 3, 40>(s_w + 20 * 256, bf, lane, kg);  // L5 40->40
        layerR<3, 3, 40>(s_w + 29 * 256, bf, lane, kg);  // L6 40->40
        layerR<3, 2, 20>(s_w + 38 * 256, bf, lane, kg);  // L7 40->20
        layerR<2, 1, 10>(s_w + 44 * 256, bf, lane, kg);  // L8 20->10

        // L9 (10->1) + ReLU: feature 0 at kg==0, reg 0; sample = lr.
        {
            const half4 wg = *(const half4*)(s_w + 46 * 256 + lane * 4);
#pragma unroll
            for (int t = 0; t < T; ++t) {
                f32x4 F = __builtin_amdgcn_mfma_f32_16x16x16f16(
                    wg, bf[t][0], z4, 0, 0, 0);
                if (kg == 0) out[row0 + t * 16 + lr] = fmaxf(F[0], 0.0f);
            }
        }
    }
}

extern "C" void kernel_launch(void* const* d_in, const int* in_sizes, int n_in,
                              void* d_out, int out_size, void* d_ws, size_t ws_size,
                              hipStream_t stream) {
    const float* x = (const float*)d_in[0];
    const float* W0 = (const float*)d_in[1];
    const float* b0 = (const float*)d_in[2];
    const float* W1 = (const float*)d_in[3];
    const float* b1 = (const float*)d_in[4];
    const float* W2 = (const float*)d_in[5];
    const float* b2 = (const float*)d_in[6];
    const float* W3 = (const float*)d_in[7];
    const float* b3 = (const float*)d_in[8];
    const float* W4 = (const float*)d_in[9];
    const float* b4 = (const float*)d_in[10];
    const float* W5 = (const float*)d_in[11];
    const float* b5 = (const float*)d_in[12];
    const float* W6 = (const float*)d_in[13];
    const float* b6 = (const float*)d_in[14];
    const float* W7 = (const float*)d_in[15];
    const float* b7 = (const float*)d_in[16];
    const float* W8 = (const float*)d_in[17];
    const float* b8 = (const float*)d_in[18];
    const float* W9 = (const float*)d_in[19];
    const float* b9 = (const float*)d_in[20];
    float* out = (float*)d_out;

    const int n = in_sizes[0] / 11;  // 2,000,000 rows (divisible by 32)
    const int grid = 1024;           // persistent grid-stride

    longnet_mlp_r18<<<grid, 256, 0, stream>>>(
        x, W0, b0, W1, b1, W2, b2, W3, b3, W4, b4, W5, b5, W6, b6, W7, b7, W8,
        b8, W9, b9, out, n);
}

// Round 19
// 176.762 us; speedup vs baseline: 1.3664x; 1.0070x over previous
//
#include <hip/hip_runtime.h>
#include <math.h>

// 10-layer MLP, ALL-K16 MFMA (16x16x16f16), activations REGISTER-RESIDENT.
// Structure (validated R11-R18): D-layout of 16x16x16f16 == its B-frag
// layout, so layers chain acc->B-frag entirely in registers; LDS holds 47
// x16 weight frags (24 KB, linear b64 reads, 0 bank conflicts); bias via
// augmented-K column + 1.0 marker; packed-f32 swish (R18: cut VALU busy
// 154->127us).
// R19: grid 1536 (was 1024). R17 (grid 1536) reached 74% VALUBusy; R18
// (grid 1024) only 60% on fewer instructions. This round tests whether the
// two measured bests compose: busy-floor 127us x best busy 74% ~= 172us
// rocprof (~150 bench). Everything else identical to R18.

typedef _Float16 half4 __attribute__((ext_vector_type(4)));
typedef _Float16 half2 __attribute__((ext_vector_type(2)));
typedef float f32x4 __attribute__((ext_vector_type(4)));
typedef float f32x2 __attribute__((ext_vector_type(2)));

#define T 2  // 16-row tiles in flight per wave

// swish on 2 elements at once: packed muls/adds + 2 trans each.
__device__ __forceinline__ f32x2 swish2(f32x2 a) {
    const f32x2 nl2e = {-1.442695041f, -1.442695041f};
    f32x2 t = a * nl2e;  // v_pk_mul_f32
    f32x2 e = {__builtin_amdgcn_exp2f(t.x), __builtin_amdgcn_exp2f(t.y)};
    const f32x2 one = {1.0f, 1.0f};
    f32x2 d = e + one;  // v_pk_add_f32
    f32x2 r = {__builtin_amdgcn_rcpf(d.x), __builtin_amdgcn_rcpf(d.y)};
    return a * r;  // v_pk_mul_f32
}

__device__ __forceinline__ half4 pack4v(f32x2 lo, f32x2 hi) {
    auto l = __builtin_amdgcn_cvt_pkrtz(lo.x, lo.y);
    auto h = __builtin_amdgcn_cvt_pkrtz(hi.x, hi.y);
    union {
        half4 h4;
        half2 h2[2];
    } u;
    u.h2[0] = __builtin_bit_cast(half2, l);
    u.h2[1] = __builtin_bit_cast(half2, h);
    return u.h4;
}

// x16 weight frag (K=16, k=kb+kg*4+e): row=ot*16+lr; k==IN -> bias.
__device__ __forceinline__ half4 make_frag16(const float* __restrict__ W,
                                             const float* __restrict__ b,
                                             int IN, int OUT, int ot, int kb,
                                             int lr, int kg) {
    const int r = ot * 16 + lr;
    half4 h;
#pragma unroll
    for (int e = 0; e < 4; ++e) {
        const int k = kb + kg * 4 + e;
        float v = 0.0f;
        if (r < OUT) {
            if (k < IN)
                v = W[r * IN + k];
            else if (k == IN)
                v = b[r];
        }
        h[e] = (_Float16)v;
    }
    return h;
}

// One layer for all T tiles, register-chained.
// bf[t][0..NKT-1] in (x16 B-frag layout) -> bf[t][0..NOT-1] out.
// MARK = OUT = next layer's bias column; prunes to one cndmask.
template <int NKT, int NOT, int MARK>
__device__ __forceinline__ void layerR(const _Float16* __restrict__ wb,
                                       half4 (&bf)[T][3], int lane, int kg) {
    const f32x4 z4 = {0.f, 0.f, 0.f, 0.f};
    f32x4 acc[T][NOT];
#pragma unroll
    for (int kt = 0; kt < NKT; ++kt) {
#pragma unroll
        for (int ot = 0; ot < NOT; ++ot) {
            const half4 wg =
                *(const half4*)(wb + (ot * NKT + kt) * 256 + lane * 4);
#pragma unroll
            for (int t = 0; t < T; ++t)
                acc[t][ot] = __builtin_amdgcn_mfma_f32_16x16x16f16(
                    wg, bf[t][kt], kt == 0 ? z4 : acc[t][ot], 0, 0, 0);
        }
    }
#pragma unroll
    for (int t = 0; t < T; ++t) {
#pragma unroll
        for (int ot = 0; ot < NOT; ++ot) {
            f32x2 lo = {acc[t][ot][0], acc[t][ot][1]};
            f32x2 hi = {acc[t][ot][2], acc[t][ot][3]};
            lo = swish2(lo);
            hi = swish2(hi);
            if (ot == MARK / 16) {
#pragma unroll
                for (int r = 0; r < 4; ++r) {
                    if ((MARK & 15) % 4 == r) {  // compile-time r select
                        const bool m = (ot * 16 + kg * 4 + r == MARK);
                        if (r < 2) {
                            if (r == 0) lo.x = m ? 1.0f : lo.x;
                            if (r == 1) lo.y = m ? 1.0f : lo.y;
                        } else {
                            if (r == 2) hi.x = m ? 1.0f : hi.x;
                            if (r == 3) hi.y = m ? 1.0f : hi.y;
                        }
                    }
                }
            }
            bf[t][ot] = pack4v(lo, hi);
        }
    }
}

__device__ __forceinline__ half4 load_x4(const float* __restrict__ x,
                                         int row0, int lr, int kg) {
    half4 b = {};
    const float* xr = x + (size_t)(row0 + lr) * 11;
#pragma unroll
    for (int e = 0; e < 4; ++e) {
        const int k = kg * 4 + e;
        float v = (k < 11) ? xr[k] : ((k == 11) ? 1.0f : 0.0f);
        b[e] = (_Float16)v;
    }
    return b;
}

__global__ __launch_bounds__(256, 2) void longnet_mlp_r19(
    const float* __restrict__ x,
    const float* __restrict__ W0, const float* __restrict__ b0,
    const float* __restrict__ W1, const float* __restrict__ b1,
    const float* __restrict__ W2, const float* __restrict__ b2,
    const float* __restrict__ W3, const float* __restrict__ b3,
    const float* __restrict__ W4, const float* __restrict__ b4,
    const float* __restrict__ W5, const float* __restrict__ b5,
    const float* __restrict__ W6, const float* __restrict__ b6,
    const float* __restrict__ W7, const float* __restrict__ b7,
    const float* __restrict__ W8, const float* __restrict__ b8,
    const float* __restrict__ W9, const float* __restrict__ b9,
    float* __restrict__ out, int n) {
    // LDS: 47 x16 weight frags x 512 B = 24064 B. No activation LDS.
    __shared__ __align__(16) _Float16 s_w[47 * 256];

    const int tid = threadIdx.x;
    const int lane = tid & 63;
    const int wave = tid >> 6;
    const int lr = lane & 15;
    const int kg = lane >> 4;

    // ---- stage 47 weight frags (4 waves round-robin) ----
    {
        const float* Wt[10] = {W0, W1, W2, W3, W4, W5, W6, W7, W8, W9};
        const float* bt[10] = {b0, b1, b2, b3, b4, b5, b6, b7, b8, b9};
        const int INs[10] = {11, 20, 20, 30, 30, 40, 40, 40, 20, 10};
        const int OUTs[10] = {20, 20, 30, 30, 40, 40, 40, 20, 10, 1};
        const int NOTs[10] = {2, 2, 2, 2, 3, 3, 3, 2, 1, 1};
        const int NKTs[10] = {1, 2, 2, 2, 2, 3, 3, 3, 2, 1};
        int f = 0;
        for (int L = 0; L < 10; ++L)
            for (int ot = 0; ot < NOTs[L]; ++ot)
                for (int kt = 0; kt < NKTs[L]; ++kt, ++f)
                    if ((f & 3) == wave) {
                        half4 h = make_frag16(Wt[L], bt[L], INs[L], OUTs[L],
                                              ot, kt * 16, lr, kg);
                        *(half4*)(s_w + f * 256 + lane * 4) = h;
                    }
    }
    __syncthreads();

    const f32x4 z4 = {0.f, 0.f, 0.f, 0.f};
    const int ngrp = n >> 5;  // 32-row groups; n = 2e6 -> 62500 exact
    const int step = (int)gridDim.x * 4;

    for (int g = blockIdx.x * 4 + wave; g < ngrp; g += step) {
        const int row0 = g * 32;

        half4 bf[T][3];
#pragma unroll
        for (int t = 0; t < T; ++t)
            bf[t][0] = load_x4(x, row0 + t * 16, lr, kg);

        layerR<1, 2, 20>(s_w + 0 * 256, bf, lane, kg);   // L0 11->20
        layerR<2, 2, 20>(s_w + 2 * 256, bf, lane, kg);   // L1 20->20
        layerR<2, 2, 30>(s_w + 6 * 256, bf, lane, kg);   // L2 20->30
        layerR<2, 2, 30>(s_w + 10 * 256, bf, lane, kg);  // L3 30->30
        layerR<2, 3, 40>(s_w + 14 * 256, bf, lane, kg);  // L4 30->40
        layerR<3, 3, 40>(s_w + 20 * 256, bf, lane, kg);  // L5 40->40
        layerR<3, 3, 40>(s_w + 29 * 256, bf, lane, kg);  // L6 40->40
        layerR<3, 2, 20>(s_w + 38 * 256, bf, lane, kg);  // L7 40->20
        layerR<2, 1, 10>(s_w + 44 * 256, bf, lane, kg);  // L8 20->10

        // L9 (10->1) + ReLU: feature 0 at kg==0, reg 0; sample = lr.
        {
            const half4 wg = *(const half4*)(s_w + 46 * 256 + lane * 4);
#pragma unroll
            for (int t = 0; t < T; ++t) {
                f32x4 F = __builtin_amdgcn_mfma_f32_16x16x16f16(
                    wg, bf[t][0], z4, 0, 0, 0);
                if (kg == 0) out[row0 + t * 16 + lr] = fmaxf(F[0], 0.0f);
            }
        }
    }
}

extern "C" void kernel_launch(void* const* d_in, const int* in_sizes, int n_in,
                              void* d_out, int out_size, void* d_ws, size_t ws_size,
                              hipStream_t stream) {
    const float* x = (const float*)d_in[0];
    const float* W0 = (const float*)d_in[1];
    const float* b0 = (const float*)d_in[2];
    const float* W1 = (const float*)d_in[3];
    const float* b1 = (const float*)d_in[4];
    const float* W2 = (const float*)d_in[5];
    const float* b2 = (const float*)d_in[6];
    const float* W3 = (const float*)d_in[7];
    const float* b3 = (const float*)d_in[8];
    const float* W4 = (const float*)d_in[9];
    const float* b4 = (const float*)d_in[10];
    const float* W5 = (const float*)d_in[11];
    const float* b5 = (const float*)d_in[12];
    const float* W6 = (const float*)d_in[13];
    const float* b6 = (const float*)d_in[14];
    const float* W7 = (const float*)d_in[15];
    const float* b7 = (const float*)d_in[16];
    const float* W8 = (const float*)d_in[17];
    const float* b8 = (const float*)d_in[18];
    const float* W9 = (const float*)d_in[19];
    const float* b9 = (const float*)d_in[20];
    float* out = (float*)d_out;

    const int n = in_sizes[0] / 11;  // 2,000,000 rows (divisible by 32)
    const int grid = 1536;           // 6 candidate blocks/CU (R17's best-busy
                                     // config); reg cap decides residency

    longnet_mlp_r19<<<grid, 256, 0, stream>>>(
        x, W0, b0, W1, b1, W2, b2, W3, b3, W4, b4, W5, b5, W6, b6, W7, b7, W8,
        b8, W9, b9, out, n);
}